// Round 4
// baseline (677.926 us; speedup 1.0000x reference)
//
#include <hip/hip_runtime.h>
#include <hip/hip_bf16.h>
#include <stdint.h>

// ---------- types ----------
typedef __bf16 bf16x8 __attribute__((ext_vector_type(8)));
typedef float floatx4 __attribute__((ext_vector_type(4)));
typedef unsigned short u16x8v __attribute__((ext_vector_type(8)));

__device__ __forceinline__ ushort f2bf(float f) {
  union { float f; uint32_t u; } v; v.f = f;
  uint32_t r = (v.u + 0x7fffu + ((v.u >> 16) & 1u)) >> 16;
  return (ushort)r;
}

__device__ __forceinline__ void load_lds16(const ushort* g, ushort* l) {
  __builtin_amdgcn_global_load_lds(
      (__attribute__((address_space(1))) void*)g,
      (__attribute__((address_space(3))) void*)l, 16, 0, 0);
}

__device__ __forceinline__ float leaky(float x) { return x >= 0.f ? x : 0.01f * x; }

__device__ __forceinline__ u16x8v lnpack(float4 xa, float4 xb, float4 sa, float4 sb,
                                         float4 ba, float4 bb, float m, float rv) {
  u16x8v o;
  o[0] = f2bf(leaky((xa.x - m) * rv * sa.x + ba.x));
  o[1] = f2bf(leaky((xa.y - m) * rv * sa.y + ba.y));
  o[2] = f2bf(leaky((xa.z - m) * rv * sa.z + ba.z));
  o[3] = f2bf(leaky((xa.w - m) * rv * sa.w + ba.w));
  o[4] = f2bf(leaky((xb.x - m) * rv * sb.x + bb.x));
  o[5] = f2bf(leaky((xb.y - m) * rv * sb.y + bb.y));
  o[6] = f2bf(leaky((xb.z - m) * rv * sb.z + bb.z));
  o[7] = f2bf(leaky((xb.w - m) * rv * sb.w + bb.w));
  return o;
}

// ---------- kernel 1: per-row LN stats -> stats[32768][4] = {m1, r1, m2, r2} ----------
__global__ __launch_bounds__(256) void stats_kernel(
    const float* __restrict__ x1, const float* __restrict__ x2,
    float* __restrict__ stats) {
  const int wid = (blockIdx.x << 2) + (threadIdx.x >> 6);  // 0..8191
  const int lane = threadIdx.x & 63;
#pragma unroll
  for (int it = 0; it < 2; ++it) {
    const int rA = wid + it * 16384;
    const int rB = rA + 8192;
    const float4* XA1 = (const float4*)(x1 + (size_t)rA * 1024);
    const float4* XA2 = (const float4*)(x2 + (size_t)rA * 512);
    const float4* XB1 = (const float4*)(x1 + (size_t)rB * 1024);
    const float4* XB2 = (const float4*)(x2 + (size_t)rB * 512);
    float sA1 = 0.f, qA1 = 0.f, sA2 = 0.f, qA2 = 0.f;
    float sB1 = 0.f, qB1 = 0.f, sB2 = 0.f, qB2 = 0.f;
#pragma unroll
    for (int j = 0; j < 4; j++) {
      const float4 a = XA1[j * 64 + lane];
      const float4 b = XB1[j * 64 + lane];
      sA1 += a.x + a.y + a.z + a.w;
      qA1 += a.x * a.x + a.y * a.y + a.z * a.z + a.w * a.w;
      sB1 += b.x + b.y + b.z + b.w;
      qB1 += b.x * b.x + b.y * b.y + b.z * b.z + b.w * b.w;
    }
#pragma unroll
    for (int j = 0; j < 2; j++) {
      const float4 a = XA2[j * 64 + lane];
      const float4 b = XB2[j * 64 + lane];
      sA2 += a.x + a.y + a.z + a.w;
      qA2 += a.x * a.x + a.y * a.y + a.z * a.z + a.w * a.w;
      sB2 += b.x + b.y + b.z + b.w;
      qB2 += b.x * b.x + b.y * b.y + b.z * b.z + b.w * b.w;
    }
#pragma unroll
    for (int o = 1; o < 64; o <<= 1) {
      sA1 += __shfl_xor(sA1, o); qA1 += __shfl_xor(qA1, o);
      sA2 += __shfl_xor(sA2, o); qA2 += __shfl_xor(qA2, o);
      sB1 += __shfl_xor(sB1, o); qB1 += __shfl_xor(qB1, o);
      sB2 += __shfl_xor(sB2, o); qB2 += __shfl_xor(qB2, o);
    }
    if (lane == 0) {
      const float mA1 = sA1 * (1.0f / 1024.0f);
      const float vA1 = rsqrtf(qA1 * (1.0f / 1024.0f) - mA1 * mA1 + 1e-6f);
      const float mA2 = sA2 * (1.0f / 512.0f);
      const float vA2 = rsqrtf(qA2 * (1.0f / 512.0f) - mA2 * mA2 + 1e-6f);
      const float mB1 = sB1 * (1.0f / 1024.0f);
      const float vB1 = rsqrtf(qB1 * (1.0f / 1024.0f) - mB1 * mB1 + 1e-6f);
      const float mB2 = sB2 * (1.0f / 512.0f);
      const float vB2 = rsqrtf(qB2 * (1.0f / 512.0f) - mB2 * mB2 + 1e-6f);
      ((float4*)stats)[rA] = make_float4(mA1, vA1, mA2, vA2);
      ((float4*)stats)[rB] = make_float4(mB1, vB1, mB2, vB2);
    }
  }
}

// ---------- kernel 2: weight transpose + cast -> WcatT[2048][1536] bf16 ----------
// UNCHANGED.
__global__ __launch_bounds__(256) void wprep_kernel(
    const float* __restrict__ Wo1, const float* __restrict__ Wo2,
    const float* __restrict__ Wg1, const float* __restrict__ Wg2,
    ushort* __restrict__ WT) {
  __shared__ float tile[32][33];
  const int k0 = blockIdx.x * 32;  // 48
  const int j0 = blockIdx.y * 32;  // 32
  const int s = blockIdx.z;        // 2
  const float* Wa = s ? Wg1 : Wo1;
  const float* Wb = s ? Wg2 : Wo2;
  const int tx = threadIdx.x;  // 0..31
  const int ty = threadIdx.y;  // 0..7
#pragma unroll
  for (int r = 0; r < 4; r++) {
    const int k = k0 + ty + 8 * r;
    const float val = (k < 1024) ? Wa[(size_t)k * 1024 + j0 + tx]
                                 : Wb[(size_t)(k - 1024) * 1024 + j0 + tx];
    tile[ty + 8 * r][tx] = val;
  }
  __syncthreads();
#pragma unroll
  for (int r = 0; r < 4; r++) {
    const int j = j0 + ty + 8 * r;
    const int c = j & 63;
    const int n = (j >> 6) * 128 + (c >> 5) * 64 + s * 32 + ((c >> 4) & 1) * 16 + (c & 15);
    WT[(size_t)n * 1536 + k0 + tx] = f2bf(tile[tx][ty + 8 * r]);
  }
}

// ---------- kernel 3: LN-fused 256x256 8-phase GEMM + bias + sigmoid-gate ----------
// A-staging now reads x1/x2 f32, applies LN(stats)+leaky+bf16 in regs, ds_write_b128
// into the SAME swizzled LDS layout (phys chunk p of row r = global chunk p^(r&7)).
// Read side / MFMA schedule / B-path / epilogue identical to round-1 (235 us).
__global__ __launch_bounds__(512, 2) void gemm_fused(
    const float* __restrict__ x1, const float* __restrict__ x2,
    const float* __restrict__ sc1p, const float* __restrict__ bi1p,
    const float* __restrict__ sc2p, const float* __restrict__ bi2p,
    const float* __restrict__ stats,  // [32768][4] m1,r1,m2,r2
    const ushort* __restrict__ Bt,    // WcatT [2048][1536] bf16
    const float* __restrict__ bo1, const float* __restrict__ bo2,
    const float* __restrict__ bg1, const float* __restrict__ bg2,
    float* __restrict__ out) {        // [32768][1024] f32
  __shared__ __align__(16) ushort As[2][16384];
  __shared__ __align__(16) ushort Bs[2][16384];
  __shared__ __align__(16) float statsL[256][4];
  const int orig = blockIdx.x;
  const int swz = (orig & 7) * 128 + (orig >> 3);  // XCD-contiguous
  const int mt = swz >> 3;
  const int nt = swz & 7;
  const int tid = threadIdx.x;
  const int wave = tid >> 6, lane = tid & 63;
  const int wr = wave >> 2, wcol = wave & 3;
  const int low = lane & 15, quad = lane >> 4;

  const size_t arow0 = (size_t)mt * 256;
  const int srow = wave * 8 + (lane >> 3);
  const int schunk = (lane & 7) ^ (lane >> 3);  // global chunk this thread provides
  const ushort* gB0 = Bt + ((size_t)nt * 256 + srow) * 1536 + schunk * 8;

  // per-s source row pointers (s = row-block 0..3 -> rows srow + 64*s)
  const float* xr1[4];
  const float* xr2[4];
#pragma unroll
  for (int s = 0; s < 4; s++) {
    xr1[s] = x1 + (arow0 + srow + 64 * s) * 1024 + schunk * 8;
    xr2[s] = x2 + (arow0 + srow + 64 * s) * 512 + schunk * 8;
  }

  // frag read offsets (swizzled) — unchanged
  const int q2 = quad ^ (low & 3);
  const int kx = (low >> 2) & 1;
  const int offA_k0 = (wr * 128 + low) * 64 + (q2 + 4 * kx) * 8;
  const int offA_k1 = (wr * 128 + low) * 64 + (q2 + 4 * (1 - kx)) * 8;
  const int offB_k0 = (wcol * 64 + low) * 64 + (q2 + 4 * kx) * 8;
  const int offB_k1 = (wcol * 64 + low) * 64 + (q2 + 4 * (1 - kx)) * 8;

  floatx4 acc[8][4];
#pragma unroll
  for (int m = 0; m < 8; m++)
#pragma unroll
    for (int n = 0; n < 4; n++) acc[m][n] = (floatx4)0.0f;

  // stage two row-blocks (S0, S0+1) of A tile KT into buffer NB, LN applied
#define STAGE_A2(NB, S0, ST1_, KO_, SA, SB, BA, BB) do { \
    const float* ps0_ = ((ST1_) ? xr1[S0] : xr2[S0]) + (KO_); \
    const float* ps1_ = ((ST1_) ? xr1[(S0) + 1] : xr2[(S0) + 1]) + (KO_); \
    const float4 x0a_ = ((const float4*)ps0_)[0], x0b_ = ((const float4*)ps0_)[1]; \
    const float4 x1a_ = ((const float4*)ps1_)[0], x1b_ = ((const float4*)ps1_)[1]; \
    const float2 mr0_ = *(const float2*)&statsL[srow + 64 * (S0)][(ST1_) ? 0 : 2]; \
    const float2 mr1_ = *(const float2*)&statsL[srow + 64 * ((S0) + 1)][(ST1_) ? 0 : 2]; \
    const u16x8v o0_ = lnpack(x0a_, x0b_, SA, SB, BA, BB, mr0_.x, mr0_.y); \
    const u16x8v o1_ = lnpack(x1a_, x1b_, SA, SB, BA, BB, mr1_.x, mr1_.y); \
    *(u16x8v*)(&As[NB][wave * 512 + (S0) * 4096 + lane * 8]) = o0_; \
    *(u16x8v*)(&As[NB][wave * 512 + ((S0) + 1) * 4096 + lane * 8]) = o1_; \
  } while (0)

#define STAGE_B(BUF, KT) do { \
    const ushort* s_ = gB0 + (KT) * 64; \
    ushort* d_ = &Bs[BUF][wave * 512]; \
    load_lds16(s_, d_); \
    load_lds16(s_ + 64 * 1536, d_ + 4096); \
    load_lds16(s_ + 128 * 1536, d_ + 8192); \
    load_lds16(s_ + 192 * 1536, d_ + 12288); \
  } while (0)

  // ---- prologue: stats cache + tile 0 (kt=0, stream1, ko=0) into buf 0 ----
  if (tid < 256) *(float4*)&statsL[tid][0] = ((const float4*)stats)[arow0 + tid];
  {
    const float* scp = sc1p + schunk * 8;
    const float* bip = bi1p + schunk * 8;
    const float4 sa = ((const float4*)scp)[0], sb = ((const float4*)scp)[1];
    const float4 ba = ((const float4*)bip)[0], bb = ((const float4*)bip)[1];
    STAGE_B(0, 0);
    // stats cache must be visible to this thread's own reads: it wrote statsL[tid]
    // but reads statsL[srow+...] (other threads' writes) -> need barrier first.
    asm volatile("s_waitcnt lgkmcnt(0)" ::: "memory");
    __builtin_amdgcn_s_barrier();
    STAGE_A2(0, 0, true, 0, sa, sb, ba, bb);
    STAGE_A2(0, 2, true, 0, sa, sb, ba, bb);
  }
  asm volatile("s_waitcnt vmcnt(0) lgkmcnt(0)" ::: "memory");
  __builtin_amdgcn_s_barrier();
  asm volatile("" ::: "memory");

#define MFMA16(MBASE) do { \
    __builtin_amdgcn_s_setprio(1); \
    _Pragma("unroll") for (int m = 0; m < 4; m++) \
      _Pragma("unroll") for (int n = 0; n < 4; n++) \
        acc[m + (MBASE)][n] = __builtin_amdgcn_mfma_f32_16x16x32_bf16(a[m], b[n], acc[m + (MBASE)][n], 0, 0, 0); \
    __builtin_amdgcn_s_setprio(0); \
  } while (0)

#define TILE_STEP(CUR, T) do { \
    const ushort* Ac = &As[CUR][0]; \
    const ushort* Bc = &Bs[CUR][0]; \
    const bool pf = (T) < 23; \
    const int ktn = (T) + 1; \
    const bool st1 = ktn < 16; \
    const int ko = (st1 ? ktn : ktn - 16) * 64; \
    float4 sa, sb, ba, bb; \
    if (pf) { \
      const float* scp = (st1 ? sc1p : sc2p) + ko + schunk * 8; \
      const float* bip = (st1 ? bi1p : bi2p) + ko + schunk * 8; \
      sa = ((const float4*)scp)[0]; sb = ((const float4*)scp)[1]; \
      ba = ((const float4*)bip)[0]; bb = ((const float4*)bip)[1]; \
    } \
    bf16x8 a[4], b[4]; \
    /* ---- PH0: stage A s0,s1 (t+1); frag A k0 m0-3 + B k0 ---- */ \
    if (pf) STAGE_A2((CUR) ^ 1, 0, st1, ko, sa, sb, ba, bb); \
    _Pragma("unroll") for (int m = 0; m < 4; m++) a[m] = *(const bf16x8*)(Ac + offA_k0 + m * 1024); \
    _Pragma("unroll") for (int n = 0; n < 4; n++) b[n] = *(const bf16x8*)(Bc + offB_k0 + n * 1024); \
    asm volatile("" ::: "memory"); \
    __builtin_amdgcn_s_barrier(); \
    MFMA16(0); \
    asm volatile("" ::: "memory"); \
    __builtin_amdgcn_s_barrier(); \
    /* ---- PH1: stage A s2,s3 (t+1) + B gloads (t+1); frag A k0 m4-7 ---- */ \
    if (pf) STAGE_A2((CUR) ^ 1, 2, st1, ko, sa, sb, ba, bb); \
    if (pf) STAGE_B((CUR) ^ 1, ktn); \
    _Pragma("unroll") for (int m = 0; m < 4; m++) a[m] = *(const bf16x8*)(Ac + offA_k0 + (m + 4) * 1024); \
    asm volatile("" ::: "memory"); \
    __builtin_amdgcn_s_barrier(); \
    MFMA16(4); \
    asm volatile("" ::: "memory"); \
    __builtin_amdgcn_s_barrier(); \
    /* ---- PH2: frag A k1 m0-3 + B k1 ---- */ \
    _Pragma("unroll") for (int m = 0; m < 4; m++) a[m] = *(const bf16x8*)(Ac + offA_k1 + m * 1024); \
    _Pragma("unroll") for (int n = 0; n < 4; n++) b[n] = *(const bf16x8*)(Bc + offB_k1 + n * 1024); \
    asm volatile("" ::: "memory"); \
    __builtin_amdgcn_s_barrier(); \
    MFMA16(0); \
    asm volatile("" ::: "memory"); \
    __builtin_amdgcn_s_barrier(); \
    /* ---- PH3: frag A k1 m4-7; boundary: drain B gloads + A ds_writes ---- */ \
    _Pragma("unroll") for (int m = 0; m < 4; m++) a[m] = *(const bf16x8*)(Ac + offA_k1 + (m + 4) * 1024); \
    asm volatile("" ::: "memory"); \
    __builtin_amdgcn_s_barrier(); \
    MFMA16(4); \
    asm volatile("s_waitcnt vmcnt(0) lgkmcnt(0)" ::: "memory"); \
    __builtin_amdgcn_s_barrier(); \
    asm volatile("" ::: "memory"); \
  } while (0)

  for (int tt = 0; tt < 12; tt++) {
    TILE_STEP(0, 2 * tt);
    TILE_STEP(1, 2 * tt + 1);
  }
#undef TILE_STEP
#undef MFMA16
#undef STAGE_A2
#undef STAGE_B

  // epilogue: frag n in {0,1} = S, frag n+2 = G of the same out columns
  const int colbase = (nt * 4 + wcol) << 5;
#pragma unroll
  for (int n = 0; n < 2; n++) {
    const int col = colbase + n * 16 + low;
    const float bs = bo1[col] + bo2[col];
    const float bg = bg1[col] + bg2[col];
#pragma unroll
    for (int m = 0; m < 8; m++) {
      const floatx4 S = acc[m][n];
      const floatx4 G = acc[m][n + 2];
      const size_t rb = (size_t)mt * 256 + wr * 128 + m * 16 + quad * 4;
#pragma unroll
      for (int r = 0; r < 4; r++) {
        const float sv = S[r] + bs;
        const float gv = G[r] + bg;
        const float gate = 1.0f / (1.0f + __expf(-gv));
        out[(rb + r) * 1024 + col] = gate * sv;
      }
    }
  }
}

extern "C" void kernel_launch(void* const* d_in, const int* in_sizes, int n_in,
                              void* d_out, int out_size, void* d_ws, size_t ws_size,
                              hipStream_t stream) {
  const float* x1 = (const float*)d_in[0];
  const float* x2 = (const float*)d_in[1];
  const float* ln_s1 = (const float*)d_in[2];
  const float* ln_b1 = (const float*)d_in[3];
  const float* ln_s2 = (const float*)d_in[4];
  const float* ln_b2 = (const float*)d_in[5];
  const float* W_out1 = (const float*)d_in[6];
  const float* b_out1 = (const float*)d_in[7];
  const float* W_out2 = (const float*)d_in[8];
  const float* b_out2 = (const float*)d_in[9];
  const float* W_g1 = (const float*)d_in[10];
  const float* b_g1 = (const float*)d_in[11];
  const float* W_g2 = (const float*)d_in[12];
  const float* b_g2 = (const float*)d_in[13];
  float* out = (float*)d_out;

  ushort* WT = (ushort*)d_ws;                          // [2048][1536] bf16 = 6 MB
  float* stats = (float*)((char*)d_ws + 6291456);      // [32768][4] f32 = 512 KB

  stats_kernel<<<2048, 256, 0, stream>>>(x1, x2, stats);
  wprep_kernel<<<dim3(48, 32, 2), dim3(32, 8), 0, stream>>>(W_out1, W_out2, W_g1, W_g2, WT);
  gemm_fused<<<dim3(1024), dim3(512), 0, stream>>>(
      x1, x2, ln_s1, ln_b1, ln_s2, ln_b2, stats, WT,
      b_out1, b_out2, b_g1, b_g2, out);
}

// Round 5
// 519.067 us; speedup vs baseline: 1.3060x; 1.3060x over previous
//
#include <hip/hip_runtime.h>
#include <hip/hip_bf16.h>
#include <stdint.h>

// ---------- types ----------
typedef __bf16 bf16x8 __attribute__((ext_vector_type(8)));
typedef float floatx4 __attribute__((ext_vector_type(4)));

__device__ __forceinline__ ushort f2bf(float f) {
  union { float f; uint32_t u; } v; v.f = f;
  uint32_t r = (v.u + 0x7fffu + ((v.u >> 16) & 1u)) >> 16;
  return (ushort)r;
}

__device__ __forceinline__ void load_lds16(const ushort* g, ushort* l) {
  __builtin_amdgcn_global_load_lds(
      (__attribute__((address_space(1))) void*)g,
      (__attribute__((address_space(3))) void*)l, 16, 0, 0);
}

__device__ __forceinline__ float leaky(float x) { return x >= 0.f ? x : 0.01f * x; }

// ---------- kernel 1: fused two-stream LayerNorm + leaky_relu -> bf16 f[B,1536] ----------
// R3 version (2048 blocks, 2-row ILP per wave). ~50 us class; not the bottleneck.
__global__ __launch_bounds__(256) void ln2_kernel(
    const float* __restrict__ x1, const float* __restrict__ x2,
    const float* __restrict__ sc1p, const float* __restrict__ bi1p,
    const float* __restrict__ sc2p, const float* __restrict__ bi2p,
    ushort* __restrict__ f) {
  const int wid = (blockIdx.x << 2) + (threadIdx.x >> 6);  // 0..8191
  const int lane = threadIdx.x & 63;

  float4 sc1[4], bi1[4], sc2[2], bi2[2];
#pragma unroll
  for (int j = 0; j < 4; j++) {
    sc1[j] = ((const float4*)sc1p)[j * 64 + lane];
    bi1[j] = ((const float4*)bi1p)[j * 64 + lane];
  }
#pragma unroll
  for (int j = 0; j < 2; j++) {
    sc2[j] = ((const float4*)sc2p)[j * 64 + lane];
    bi2[j] = ((const float4*)bi2p)[j * 64 + lane];
  }

#pragma unroll
  for (int it = 0; it < 2; ++it) {
    const int rA = wid + it * 16384;
    const int rB = rA + 8192;
    const float4* XA1 = (const float4*)(x1 + (size_t)rA * 1024);
    const float4* XA2 = (const float4*)(x2 + (size_t)rA * 512);
    const float4* XB1 = (const float4*)(x1 + (size_t)rB * 1024);
    const float4* XB2 = (const float4*)(x2 + (size_t)rB * 512);
    float4 a1[4], a2[2], b1[4], b2[2];
#pragma unroll
    for (int j = 0; j < 4; j++) a1[j] = XA1[j * 64 + lane];
#pragma unroll
    for (int j = 0; j < 2; j++) a2[j] = XA2[j * 64 + lane];
#pragma unroll
    for (int j = 0; j < 4; j++) b1[j] = XB1[j * 64 + lane];
#pragma unroll
    for (int j = 0; j < 2; j++) b2[j] = XB2[j * 64 + lane];

    float sA1 = 0.f, qA1 = 0.f, sA2 = 0.f, qA2 = 0.f;
    float sB1 = 0.f, qB1 = 0.f, sB2 = 0.f, qB2 = 0.f;
#pragma unroll
    for (int j = 0; j < 4; j++) {
      sA1 += a1[j].x + a1[j].y + a1[j].z + a1[j].w;
      qA1 += a1[j].x * a1[j].x + a1[j].y * a1[j].y + a1[j].z * a1[j].z + a1[j].w * a1[j].w;
      sB1 += b1[j].x + b1[j].y + b1[j].z + b1[j].w;
      qB1 += b1[j].x * b1[j].x + b1[j].y * b1[j].y + b1[j].z * b1[j].z + b1[j].w * b1[j].w;
    }
#pragma unroll
    for (int j = 0; j < 2; j++) {
      sA2 += a2[j].x + a2[j].y + a2[j].z + a2[j].w;
      qA2 += a2[j].x * a2[j].x + a2[j].y * a2[j].y + a2[j].z * a2[j].z + a2[j].w * a2[j].w;
      sB2 += b2[j].x + b2[j].y + b2[j].z + b2[j].w;
      qB2 += b2[j].x * b2[j].x + b2[j].y * b2[j].y + b2[j].z * b2[j].z + b2[j].w * b2[j].w;
    }
#pragma unroll
    for (int o = 1; o < 64; o <<= 1) {
      sA1 += __shfl_xor(sA1, o); qA1 += __shfl_xor(qA1, o);
      sA2 += __shfl_xor(sA2, o); qA2 += __shfl_xor(qA2, o);
      sB1 += __shfl_xor(sB1, o); qB1 += __shfl_xor(qB1, o);
      sB2 += __shfl_xor(sB2, o); qB2 += __shfl_xor(qB2, o);
    }
    const float mA1 = sA1 * (1.0f / 1024.0f);
    const float rA1 = rsqrtf(qA1 * (1.0f / 1024.0f) - mA1 * mA1 + 1e-6f);
    const float mA2 = sA2 * (1.0f / 512.0f);
    const float rA2v = rsqrtf(qA2 * (1.0f / 512.0f) - mA2 * mA2 + 1e-6f);
    const float mB1 = sB1 * (1.0f / 1024.0f);
    const float rB1 = rsqrtf(qB1 * (1.0f / 1024.0f) - mB1 * mB1 + 1e-6f);
    const float mB2 = sB2 * (1.0f / 512.0f);
    const float rB2v = rsqrtf(qB2 * (1.0f / 512.0f) - mB2 * mB2 + 1e-6f);

    ushort* fA = f + (size_t)rA * 1536;
    ushort* fB = f + (size_t)rB * 1536;
#pragma unroll
    for (int j = 0; j < 4; j++) {
      ushort4 oA, oB;
      oA.x = f2bf(leaky((a1[j].x - mA1) * rA1 * sc1[j].x + bi1[j].x));
      oA.y = f2bf(leaky((a1[j].y - mA1) * rA1 * sc1[j].y + bi1[j].y));
      oA.z = f2bf(leaky((a1[j].z - mA1) * rA1 * sc1[j].z + bi1[j].z));
      oA.w = f2bf(leaky((a1[j].w - mA1) * rA1 * sc1[j].w + bi1[j].w));
      oB.x = f2bf(leaky((b1[j].x - mB1) * rB1 * sc1[j].x + bi1[j].x));
      oB.y = f2bf(leaky((b1[j].y - mB1) * rB1 * sc1[j].y + bi1[j].y));
      oB.z = f2bf(leaky((b1[j].z - mB1) * rB1 * sc1[j].z + bi1[j].z));
      oB.w = f2bf(leaky((b1[j].w - mB1) * rB1 * sc1[j].w + bi1[j].w));
      ((ushort4*)fA)[j * 64 + lane] = oA;
      ((ushort4*)fB)[j * 64 + lane] = oB;
    }
#pragma unroll
    for (int j = 0; j < 2; j++) {
      ushort4 oA, oB;
      oA.x = f2bf(leaky((a2[j].x - mA2) * rA2v * sc2[j].x + bi2[j].x));
      oA.y = f2bf(leaky((a2[j].y - mA2) * rA2v * sc2[j].y + bi2[j].y));
      oA.z = f2bf(leaky((a2[j].z - mA2) * rA2v * sc2[j].z + bi2[j].z));
      oA.w = f2bf(leaky((a2[j].w - mA2) * rA2v * sc2[j].w + bi2[j].w));
      oB.x = f2bf(leaky((b2[j].x - mB2) * rB2v * sc2[j].x + bi2[j].x));
      oB.y = f2bf(leaky((b2[j].y - mB2) * rB2v * sc2[j].y + bi2[j].y));
      oB.z = f2bf(leaky((b2[j].z - mB2) * rB2v * sc2[j].z + bi2[j].z));
      oB.w = f2bf(leaky((b2[j].w - mB2) * rB2v * sc2[j].w + bi2[j].w));
      ((ushort4*)(fA + 1024))[j * 64 + lane] = oA;
      ((ushort4*)(fB + 1024))[j * 64 + lane] = oB;
    }
  }
}

// ---------- kernel 2: weight transpose + cast -> WcatT[2048][1536] bf16 ----------
// UNCHANGED.
__global__ __launch_bounds__(256) void wprep_kernel(
    const float* __restrict__ Wo1, const float* __restrict__ Wo2,
    const float* __restrict__ Wg1, const float* __restrict__ Wg2,
    ushort* __restrict__ WT) {
  __shared__ float tile[32][33];
  const int k0 = blockIdx.x * 32;  // 48
  const int j0 = blockIdx.y * 32;  // 32
  const int s = blockIdx.z;        // 2
  const float* Wa = s ? Wg1 : Wo1;
  const float* Wb = s ? Wg2 : Wo2;
  const int tx = threadIdx.x;  // 0..31
  const int ty = threadIdx.y;  // 0..7
#pragma unroll
  for (int r = 0; r < 4; r++) {
    const int k = k0 + ty + 8 * r;
    const float val = (k < 1024) ? Wa[(size_t)k * 1024 + j0 + tx]
                                 : Wb[(size_t)(k - 1024) * 1024 + j0 + tx];
    tile[ty + 8 * r][tx] = val;
  }
  __syncthreads();
#pragma unroll
  for (int r = 0; r < 4; r++) {
    const int j = j0 + ty + 8 * r;
    const int c = j & 63;
    const int n = (j >> 6) * 128 + (c >> 5) * 64 + s * 32 + ((c >> 4) & 1) * 16 + (c & 15);
    WT[(size_t)n * 1536 + k0 + tx] = f2bf(tile[tx][ty + 8 * r]);
  }
}

// ---------- kernel 3: 256x256 8-phase GEMM + bias + sigmoid-gate ----------
// Round-5 change vs best (R1/R3 gemm, 235us): B is TRIPLE-buffered (A 2 x 32KB +
// B 3 x 32KB = 160 KiB LDS exactly). Per tile t: PH0 issues A(t+1), PH1 issues
// B(t+2); boundary waits vmcnt(4) -> A(t+1) (3.5 phases slack) + B(t+1) (one full
// tile of slack) done, B(t+2)'s 4 loads stay in flight ACROSS the barrier (T4,
// issue-early + counted-wait; fixes R2's late-issue mistake). Everything else
// (offsets, swizzle, phase structure, epilogue) byte-identical to R1/R3.
__global__ __launch_bounds__(512, 2) void gemm_fused(
    const ushort* __restrict__ A,   // f [32768][1536] bf16
    const ushort* __restrict__ Bt,  // WcatT [2048][1536] bf16
    const float* __restrict__ bo1, const float* __restrict__ bo2,
    const float* __restrict__ bg1, const float* __restrict__ bg2,
    float* __restrict__ out) {      // [32768][1024] f32
  __shared__ __align__(16) ushort As[2][16384];
  __shared__ __align__(16) ushort Bs[3][16384];
  const int orig = blockIdx.x;
  const int swz = (orig & 7) * 128 + (orig >> 3);  // XCD-contiguous
  const int mt = swz >> 3;
  const int nt = swz & 7;
  const int tid = threadIdx.x;
  const int wave = tid >> 6, lane = tid & 63;
  const int wr = wave >> 2, wcol = wave & 3;
  const int low = lane & 15, quad = lane >> 4;

  const int srow = wave * 8 + (lane >> 3);
  const int schunk = (lane & 7) ^ (lane >> 3);
  const ushort* gA0 = A + ((size_t)mt * 256 + srow) * 1536 + schunk * 8;
  const ushort* gB0 = Bt + ((size_t)nt * 256 + srow) * 1536 + schunk * 8;

  const int q2 = quad ^ (low & 3);
  const int kx = (low >> 2) & 1;
  const int offA_k0 = (wr * 128 + low) * 64 + (q2 + 4 * kx) * 8;
  const int offA_k1 = (wr * 128 + low) * 64 + (q2 + 4 * (1 - kx)) * 8;
  const int offB_k0 = (wcol * 64 + low) * 64 + (q2 + 4 * kx) * 8;
  const int offB_k1 = (wcol * 64 + low) * 64 + (q2 + 4 * (1 - kx)) * 8;

  floatx4 acc[8][4];
#pragma unroll
  for (int m = 0; m < 8; m++)
#pragma unroll
    for (int n = 0; n < 4; n++) acc[m][n] = (floatx4)0.0f;

#define STAGE_A(NB, KT) do { \
    const ushort* s_ = gA0 + (KT) * 64; \
    ushort* d_ = &As[NB][wave * 512]; \
    load_lds16(s_, d_); \
    load_lds16(s_ + 64 * 1536, d_ + 4096); \
    load_lds16(s_ + 128 * 1536, d_ + 8192); \
    load_lds16(s_ + 192 * 1536, d_ + 12288); \
  } while (0)
#define STAGE_B(NB, KT) do { \
    const ushort* s_ = gB0 + (KT) * 64; \
    ushort* d_ = &Bs[NB][wave * 512]; \
    load_lds16(s_, d_); \
    load_lds16(s_ + 64 * 1536, d_ + 4096); \
    load_lds16(s_ + 128 * 1536, d_ + 8192); \
    load_lds16(s_ + 192 * 1536, d_ + 12288); \
  } while (0)

#define MFMA16(MBASE) do { \
    __builtin_amdgcn_s_setprio(1); \
    _Pragma("unroll") for (int m_ = 0; m_ < 4; m_++) \
      _Pragma("unroll") for (int n_ = 0; n_ < 4; n_++) \
        acc[m_ + (MBASE)][n_] = __builtin_amdgcn_mfma_f32_16x16x32_bf16(a[m_], b[n_], acc[m_ + (MBASE)][n_], 0, 0, 0); \
    __builtin_amdgcn_s_setprio(0); \
  } while (0)

  // ---- prologue: A(0)->As0, B(0)->Bs0, B(1)->Bs1; wait all but B(1) ----
  STAGE_A(0, 0);
  STAGE_B(0, 0);
  STAGE_B(1, 1);
  asm volatile("s_waitcnt vmcnt(4)" ::: "memory");
  __builtin_amdgcn_s_barrier();
  asm volatile("" ::: "memory");

  // main loop, fully unrolled so buffer indices fold to constants
#pragma unroll
  for (int t = 0; t < 24; ++t) {
    const ushort* Ac = &As[t & 1][0];
    const ushort* Bc = &Bs[t % 3][0];
    bf16x8 a[4], b[4];
    // ---- PH0: frag A k0 m0-3 + B k0; issue A(t+1) ----
#pragma unroll
    for (int m = 0; m < 4; m++) a[m] = *(const bf16x8*)(Ac + offA_k0 + m * 1024);
#pragma unroll
    for (int n = 0; n < 4; n++) b[n] = *(const bf16x8*)(Bc + offB_k0 + n * 1024);
    if (t < 23) STAGE_A((t + 1) & 1, t + 1);
    asm volatile("" ::: "memory");
    __builtin_amdgcn_s_barrier();
    MFMA16(0);
    asm volatile("" ::: "memory");
    __builtin_amdgcn_s_barrier();
    // ---- PH1: frag A k0 m4-7; issue B(t+2) ----
#pragma unroll
    for (int m = 0; m < 4; m++) a[m] = *(const bf16x8*)(Ac + offA_k0 + (m + 4) * 1024);
    if (t < 22) STAGE_B((t + 2) % 3, t + 2);
    asm volatile("" ::: "memory");
    __builtin_amdgcn_s_barrier();
    MFMA16(4);
    asm volatile("" ::: "memory");
    __builtin_amdgcn_s_barrier();
    // ---- PH2: frag A k1 m0-3 + B k1 ----
#pragma unroll
    for (int m = 0; m < 4; m++) a[m] = *(const bf16x8*)(Ac + offA_k1 + m * 1024);
#pragma unroll
    for (int n = 0; n < 4; n++) b[n] = *(const bf16x8*)(Bc + offB_k1 + n * 1024);
    asm volatile("" ::: "memory");
    __builtin_amdgcn_s_barrier();
    MFMA16(0);
    asm volatile("" ::: "memory");
    __builtin_amdgcn_s_barrier();
    // ---- PH3: frag A k1 m4-7; boundary: counted wait, B(t+2) stays in flight ----
#pragma unroll
    for (int m = 0; m < 4; m++) a[m] = *(const bf16x8*)(Ac + offA_k1 + (m + 4) * 1024);
    asm volatile("" ::: "memory");
    __builtin_amdgcn_s_barrier();
    MFMA16(4);
    if (t < 22) {
      asm volatile("s_waitcnt vmcnt(4)" ::: "memory");  // A(t+1)+B(t+1) done; B(t+2) in flight
      __builtin_amdgcn_s_barrier();
      asm volatile("" ::: "memory");
    } else if (t == 22) {
      asm volatile("s_waitcnt vmcnt(0)" ::: "memory");  // drain A(23)+B(23)
      __builtin_amdgcn_s_barrier();
      asm volatile("" ::: "memory");
    }
    // t == 23: nothing in flight; fall through to epilogue
  }
#undef MFMA16
#undef STAGE_A
#undef STAGE_B

  // epilogue: frag n in {0,1} = S, frag n+2 = G of the same out columns
  const int colbase = (nt * 4 + wcol) << 5;
#pragma unroll
  for (int n = 0; n < 2; n++) {
    const int col = colbase + n * 16 + low;
    const float bs = bo1[col] + bo2[col];
    const float bg = bg1[col] + bg2[col];
#pragma unroll
    for (int m = 0; m < 8; m++) {
      const floatx4 S = acc[m][n];
      const floatx4 G = acc[m][n + 2];
      const size_t rb = (size_t)mt * 256 + wr * 128 + m * 16 + quad * 4;
#pragma unroll
      for (int r = 0; r < 4; r++) {
        const float sv = S[r] + bs;
        const float gv = G[r] + bg;
        const float gate = 1.0f / (1.0f + __expf(-gv));
        out[(rb + r) * 1024 + col] = gate * sv;
      }
    }
  }
}

extern "C" void kernel_launch(void* const* d_in, const int* in_sizes, int n_in,
                              void* d_out, int out_size, void* d_ws, size_t ws_size,
                              hipStream_t stream) {
  const float* x1 = (const float*)d_in[0];
  const float* x2 = (const float*)d_in[1];
  const float* ln_s1 = (const float*)d_in[2];
  const float* ln_b1 = (const float*)d_in[3];
  const float* ln_s2 = (const float*)d_in[4];
  const float* ln_b2 = (const float*)d_in[5];
  const float* W_out1 = (const float*)d_in[6];
  const float* b_out1 = (const float*)d_in[7];
  const float* W_out2 = (const float*)d_in[8];
  const float* b_out2 = (const float*)d_in[9];
  const float* W_g1 = (const float*)d_in[10];
  const float* b_g1 = (const float*)d_in[11];
  const float* W_g2 = (const float*)d_in[12];
  const float* b_g2 = (const float*)d_in[13];
  float* out = (float*)d_out;

  ushort* f = (ushort*)d_ws;              // [32768][1536] bf16
  ushort* WT = f + (size_t)32768 * 1536;  // [2048][1536] bf16

  ln2_kernel<<<2048, 256, 0, stream>>>(x1, x2, ln_s1, ln_b1, ln_s2, ln_b2, f);
  wprep_kernel<<<dim3(48, 32, 2), dim3(32, 8), 0, stream>>>(W_out1, W_out2, W_g1, W_g2, WT);
  gemm_fused<<<dim3(1024), dim3(512), 0, stream>>>(f, WT, b_out1, b_out2, b_g1, b_g2, out);
}